// Round 4
// baseline (535.980 us; speedup 1.0000x reference)
//
#include <hip/hip_runtime.h>
#include <hip/hip_bf16.h>
#include <cstdint>
#include <cstddef>

typedef __hip_bfloat16 bf16;
typedef __attribute__((ext_vector_type(8))) __bf16 bf16x8;
typedef __attribute__((ext_vector_type(4))) float floatx4;

__device__ __forceinline__ floatx4 mfma16(bf16x8 a, bf16x8 b, floatx4 c) {
  return __builtin_amdgcn_mfma_f32_16x16x32_bf16(a, b, c, 0, 0, 0);
}

// ---------------------------------------------------------------------------
// Stage a 128x32 tile (source row stride = 1024 elements) into bf16 LDS.
// fp32 source: float4 loads -> RNE convert -> 8B LDS stores (fused cast).
// bf16 source: 16B copies.
// ---------------------------------------------------------------------------
__device__ __forceinline__ void stage_tile(const float* __restrict__ g,
                                           bf16* __restrict__ lds, int tid) {
#pragma unroll
  for (int t = 0; t < 4; ++t) {
    int idx = tid + t * 256;          // 1024 float4 chunks
    int row = idx >> 3, c4 = idx & 7;
    float4 v = *(const float4*)(g + (size_t)row * 1024 + c4 * 4);
    alignas(8) bf16 tmp[4] = {__float2bfloat16(v.x), __float2bfloat16(v.y),
                              __float2bfloat16(v.z), __float2bfloat16(v.w)};
    *(uint64_t*)&lds[row * 32 + c4 * 4] = *(const uint64_t*)tmp;
  }
}

__device__ __forceinline__ void stage_tile(const bf16* __restrict__ g,
                                           bf16* __restrict__ lds, int tid) {
#pragma unroll
  for (int t = 0; t < 2; ++t) {
    int idx = tid + t * 256;          // 512 x 16B chunks
    int row = idx >> 2, c8 = idx & 3;
    bf16x8 v = *(const bf16x8*)(g + (size_t)row * 1024 + c8 * 8);
    *(bf16x8*)&lds[row * 32 + c8 * 8] = v;
  }
}

// ---------------------------------------------------------------------------
// GEMM: out = A[M,1024] @ W[N,1024]^T, 128x128 tile, BK=32, 4 waves (2x2).
// A dtype TA (fp32 or bf16), W fp32, output dtype TO. K hard-coded 1024.
// MODE 0: out[m*1024+n] fp32               (final o-proj -> d_out)
// MODE 1: q  [B,H,T,64] bf16, scaled
// MODE 2: kv [B,G,T,64] bf16
// MODE 3: vT [B,G,64,T] bf16               (direct transposed V write)
// ---------------------------------------------------------------------------
template <int MODE, typename TA, typename TO>
__global__ __launch_bounds__(256) void gemm_bt(const TA* __restrict__ A,
                                               const float* __restrict__ W,
                                               TO* __restrict__ out,
                                               float scale) {
  __shared__ alignas(16) bf16 As[128 * 32];
  __shared__ alignas(16) bf16 Bs[128 * 32];
  const int tid = threadIdx.x;
  const int lane = tid & 63;
  const int w = tid >> 6;
  const int wr = w >> 1, wc = w & 1;
  const int quad = lane >> 4, c = lane & 15;
  const int m0 = blockIdx.y * 128, n0 = blockIdx.x * 128;

  floatx4 acc[4][4] = {};

  for (int kt = 0; kt < 32; ++kt) {
    if (kt) __syncthreads();  // protect previous iteration's fragment reads
    stage_tile(A + (size_t)m0 * 1024 + kt * 32, As, tid);
    stage_tile(W + (size_t)n0 * 1024 + kt * 32, Bs, tid);
    __syncthreads();
    bf16x8 af[4], bfr[4];
#pragma unroll
    for (int i = 0; i < 4; ++i)
      af[i] = *(const bf16x8*)&As[(wr * 64 + i * 16 + c) * 32 + quad * 8];
#pragma unroll
    for (int j = 0; j < 4; ++j)
      bfr[j] = *(const bf16x8*)&Bs[(wc * 64 + j * 16 + c) * 32 + quad * 8];
#pragma unroll
    for (int i = 0; i < 4; ++i)
#pragma unroll
      for (int j = 0; j < 4; ++j)
        acc[i][j] = mfma16(af[i], bfr[j], acc[i][j]);
  }

  if (MODE == 3) {
    // vT[((b*4+g)*64+d)*1024 + t]: 4 consecutive t per (i,j), one 8B store
#pragma unroll
    for (int i = 0; i < 4; ++i)
#pragma unroll
      for (int j = 0; j < 4; ++j) {
        int m = m0 + wr * 64 + i * 16 + quad * 4;
        int n = n0 + wc * 64 + j * 16 + c;
        int b = m >> 10, t = m & 1023, g = n >> 6, d = n & 63;
        alignas(8) bf16 tmp[4];
#pragma unroll
        for (int r = 0; r < 4; ++r) tmp[r] = __float2bfloat16(acc[i][j][r]);
        *(uint64_t*)((bf16*)out + (((size_t)(b * 4 + g)) * 64 + d) * 1024 + t) =
            *(const uint64_t*)tmp;
      }
    return;
  }

#pragma unroll
  for (int i = 0; i < 4; ++i)
#pragma unroll
    for (int j = 0; j < 4; ++j)
#pragma unroll
      for (int r = 0; r < 4; ++r) {
        int m = m0 + wr * 64 + i * 16 + quad * 4 + r;
        int n = n0 + wc * 64 + j * 16 + c;
        float v = acc[i][j][r] * scale;
        if (MODE == 0) {
          ((float*)out)[(size_t)m * 1024 + n] = v;
        } else if (MODE == 1) {
          int b = m >> 10, t = m & 1023, h = n >> 6, d = n & 63;
          ((bf16*)out)[(((size_t)(b * 16 + h)) * 1024 + t) * 64 + d] =
              __float2bfloat16(v);
        } else {
          int b = m >> 10, t = m & 1023, g = n >> 6, d = n & 63;
          ((bf16*)out)[(((size_t)(b * 4 + g)) * 1024 + t) * 64 + d] =
              __float2bfloat16(v);
        }
      }
}

// ---------------------------------------------------------------------------
// Flash attention with relative-position bias.
// grid (T/64, B*H), 256 threads: 4 independent waves x 16 q-rows.
// qE = q . E^T (E fp32, converted in-reg) -> LDS bias gather table;
// K-loop: S=QK^T (MFMA) + bias gather, online softmax, P -> LDS -> PV MFMA.
// ---------------------------------------------------------------------------
__global__ __launch_bounds__(256) void attn_kernel(const bf16* __restrict__ q_ws,
                                                   const bf16* __restrict__ k_ws,
                                                   const bf16* __restrict__ vT,
                                                   const float* __restrict__ E,
                                                   bf16* __restrict__ out) {
  __shared__ alignas(16) bf16 qEl[4][16 * 264];  // per-wave bias table, padded
  __shared__ alignas(16) bf16 Pl[4][16 * 72];    // per-wave P transpose buffer
  const int tid = threadIdx.x;
  const int lane = tid & 63, w = tid >> 6;
  const int quad = lane >> 4, c = lane & 15;
  const int bh = blockIdx.y;
  const int b = bh >> 4, h = bh & 15, g = h >> 2;
  const int q0 = blockIdx.x * 64;
  const int qb = q0 + w * 16;

  // Q fragments (A-operand layout), stay in registers
  const bf16* qrow = q_ws + ((size_t)bh * 1024 + qb + c) * 64;
  bf16x8 qf0 = *(const bf16x8*)(qrow + quad * 8);
  bf16x8 qf1 = *(const bf16x8*)(qrow + 32 + quad * 8);

  // qE[rowlocal][p] = q[row] . E[p]   (p in [0,254]; 255 clamped/unused)
  for (int jn = 0; jn < 16; ++jn) {
    int er = jn * 16 + c;
    er = er > 254 ? 254 : er;
    const float* Ep = E + (size_t)er * 64;
    float4 e0 = *(const float4*)(Ep + quad * 8);
    float4 e1 = *(const float4*)(Ep + quad * 8 + 4);
    float4 e2 = *(const float4*)(Ep + 32 + quad * 8);
    float4 e3 = *(const float4*)(Ep + 32 + quad * 8 + 4);
    alignas(16) bf16 t0b[8] = {
        __float2bfloat16(e0.x), __float2bfloat16(e0.y), __float2bfloat16(e0.z),
        __float2bfloat16(e0.w), __float2bfloat16(e1.x), __float2bfloat16(e1.y),
        __float2bfloat16(e1.z), __float2bfloat16(e1.w)};
    alignas(16) bf16 t1b[8] = {
        __float2bfloat16(e2.x), __float2bfloat16(e2.y), __float2bfloat16(e2.z),
        __float2bfloat16(e2.w), __float2bfloat16(e3.x), __float2bfloat16(e3.y),
        __float2bfloat16(e3.z), __float2bfloat16(e3.w)};
    bf16x8 ef0 = *(const bf16x8*)t0b;
    bf16x8 ef1 = *(const bf16x8*)t1b;
    floatx4 a = {};
    a = mfma16(qf0, ef0, a);
    a = mfma16(qf1, ef1, a);
#pragma unroll
    for (int r = 0; r < 4; ++r)
      qEl[w][(quad * 4 + r) * 264 + jn * 16 + c] = __float2bfloat16(a[r]);
  }
  __syncthreads();

  floatx4 o[4] = {};
  float mrow[4] = {-1e30f, -1e30f, -1e30f, -1e30f};
  float lrow[4] = {0.f, 0.f, 0.f, 0.f};

  const bf16* kbase = k_ws + (size_t)(b * 4 + g) * 1024 * 64;
  const bf16* vbase = vT + (size_t)(b * 4 + g) * 64 * 1024;

  for (int t0 = 0; t0 < 1024; t0 += 64) {
    // S[16,64] = Q . K^T (K B-fragments straight from global, L1/L2-resident)
    floatx4 S[4] = {};
#pragma unroll
    for (int j = 0; j < 4; ++j) {
      const bf16* kp = kbase + (size_t)(t0 + j * 16 + c) * 64;
      bf16x8 kf0 = *(const bf16x8*)(kp + quad * 8);
      bf16x8 kf1 = *(const bf16x8*)(kp + 32 + quad * 8);
      S[j] = mfma16(qf0, kf0, S[j]);
      S[j] = mfma16(qf1, kf1, S[j]);
    }
    // bias + online softmax (rows live within a quad: 16-lane reductions)
    float Pv[4][4];
    float al[4];
#pragma unroll
    for (int r = 0; r < 4; ++r) {
      const int qi = qb + quad * 4 + r;
      const int lr = (quad * 4 + r) * 264;
      float mx = -1e30f;
#pragma unroll
      for (int j = 0; j < 4; ++j) {
        int ki = t0 + j * 16 + c;
        int dlt = qi - ki;
        dlt = dlt > 127 ? 127 : (dlt < -127 ? -127 : dlt);
        float s = S[j][r] + __bfloat162float(qEl[w][lr + dlt + 127]);
        S[j][r] = s;
        mx = fmaxf(mx, s);
      }
      mx = fmaxf(mx, __shfl_xor(mx, 1, 64));
      mx = fmaxf(mx, __shfl_xor(mx, 2, 64));
      mx = fmaxf(mx, __shfl_xor(mx, 4, 64));
      mx = fmaxf(mx, __shfl_xor(mx, 8, 64));
      float nm = fmaxf(mrow[r], mx);
      al[r] = __expf(mrow[r] - nm);
      float rs = 0.f;
#pragma unroll
      for (int j = 0; j < 4; ++j) {
        float p = __expf(S[j][r] - nm);
        Pv[j][r] = p;
        rs += p;
      }
      rs += __shfl_xor(rs, 1, 64);
      rs += __shfl_xor(rs, 2, 64);
      rs += __shfl_xor(rs, 4, 64);
      rs += __shfl_xor(rs, 8, 64);
      lrow[r] = lrow[r] * al[r] + rs;
      mrow[r] = nm;
    }
    // P: C-layout regs -> LDS -> A-operand layout
#pragma unroll
    for (int j = 0; j < 4; ++j)
#pragma unroll
      for (int r = 0; r < 4; ++r)
        Pl[w][(quad * 4 + r) * 72 + j * 16 + c] = __float2bfloat16(Pv[j][r]);
#pragma unroll
    for (int jj = 0; jj < 4; ++jj)
#pragma unroll
      for (int r = 0; r < 4; ++r) o[jj][r] *= al[r];
    __syncthreads();
    bf16x8 pf0 = *(const bf16x8*)&Pl[w][c * 72 + quad * 8];
    bf16x8 pf1 = *(const bf16x8*)&Pl[w][c * 72 + 32 + quad * 8];
#pragma unroll
    for (int jj = 0; jj < 4; ++jj) {
      const bf16* vp = vbase + (size_t)(jj * 16 + c) * 1024 + t0;
      bf16x8 vf0 = *(const bf16x8*)(vp + quad * 8);
      bf16x8 vf1 = *(const bf16x8*)(vp + 32 + quad * 8);
      o[jj] = mfma16(pf0, vf0, o[jj]);
      o[jj] = mfma16(pf1, vf1, o[jj]);
    }
    __syncthreads();  // protect Pl from next iteration's overwrite
  }

  // epilogue: normalize, write bf16 attn [B,T,H,64] (= [8192,1024] for o-proj)
#pragma unroll
  for (int jj = 0; jj < 4; ++jj)
#pragma unroll
    for (int r = 0; r < 4; ++r) {
      int qi = qb + quad * 4 + r;
      float val = o[jj][r] / lrow[r];
      out[(((size_t)b * 1024 + qi) * 16 + h) * 64 + jj * 16 + c] =
          __float2bfloat16(val);
    }
}

// ---------------------------------------------------------------------------
// Dtypes: ALL inputs fp32, output fp32 (per reference / harness contract).
// Rounds 1-3 read fp32 buffers as bf16 -> random mantissa halfwords decode as
// bf16 NaN (p~0.4%) -> NaN everywhere. Internals stay bf16 MFMA (2% rel tol).
// d_out = 8.4M fp32 = 32 MB; q (16 MB bf16) borrows its first half, consumed
// by attn before the final fp32 o-proj overwrites d_out.
// ws: k 4MB @0 | vT 4MB @4M | attn(bf16) 16MB @8M  -> 24 MB total.
// ---------------------------------------------------------------------------
extern "C" void kernel_launch(void* const* d_in, const int* in_sizes, int n_in,
                              void* d_out, int out_size, void* d_ws,
                              size_t ws_size, hipStream_t stream) {
  const float* x = (const float*)d_in[0];
  const float* Wq = (const float*)d_in[1];
  const float* Wk = (const float*)d_in[2];
  const float* Wv = (const float*)d_in[3];
  const float* Wo = (const float*)d_in[4];
  const float* E = (const float*)d_in[5];

  char* ws = (char*)d_ws;
  bf16* q_ws = (bf16*)d_out;                 // 16 MB bf16 in 32 MB fp32 d_out
  bf16* k_ws = (bf16*)(ws);                  //  4 MB [B,G,T,64]
  bf16* vT = (bf16*)(ws + (4ull << 20));     //  4 MB [B,G,64,T]
  bf16* attn = (bf16*)(ws + (8ull << 20));   // 16 MB [B,T,H,64]
  float* outp = (float*)d_out;

  gemm_bt<1, float, bf16><<<dim3(8, 64), 256, 0, stream>>>(x, Wq, q_ws, 0.125f);
  gemm_bt<2, float, bf16><<<dim3(2, 64), 256, 0, stream>>>(x, Wk, k_ws, 1.0f);
  gemm_bt<3, float, bf16><<<dim3(2, 64), 256, 0, stream>>>(x, Wv, vT, 1.0f);
  attn_kernel<<<dim3(16, 128), 256, 0, stream>>>(q_ws, k_ws, vT, E, attn);
  gemm_bt<0, bf16, float><<<dim3(8, 64), 256, 0, stream>>>(attn, Wo, outp, 1.0f);
}

// Round 6
// 523.101 us; speedup vs baseline: 1.0246x; 1.0246x over previous
//
#include <hip/hip_runtime.h>
#include <hip/hip_bf16.h>
#include <cstdint>
#include <cstddef>

typedef __hip_bfloat16 bf16;
typedef __attribute__((ext_vector_type(8))) __bf16 bf16x8;
typedef __attribute__((ext_vector_type(4))) float floatx4;

#define GPTR(p) ((const __attribute__((address_space(1))) void*)(p))
#define LPTR(p) ((__attribute__((address_space(3))) void*)(p))

__device__ __forceinline__ floatx4 mfma16(bf16x8 a, bf16x8 b, floatx4 c) {
  return __builtin_amdgcn_mfma_f32_16x16x32_bf16(a, b, c, 0, 0, 0);
}

// ---------------------------------------------------------------------------
// fp32 -> bf16 bulk convert (x pre-cast; ~8 us, saves per-GEMM A-side casts)
// ---------------------------------------------------------------------------
__global__ __launch_bounds__(256) void cvt_bf16(const float* __restrict__ in,
                                                bf16* __restrict__ out, int n4) {
  for (int i = blockIdx.x * 256 + threadIdx.x; i < n4; i += gridDim.x * 256) {
    float4 v = ((const float4*)in)[i];
    alignas(8) bf16 t[4] = {__float2bfloat16(v.x), __float2bfloat16(v.y),
                            __float2bfloat16(v.z), __float2bfloat16(v.w)};
    *(uint64_t*)(out + (size_t)i * 4) = *(const uint64_t*)t;
  }
}

// ---------------------------------------------------------------------------
// GEMM: out = A[M,1024](bf16) @ W[N,1024](fp32)^T. 128x128 tile, BK=32,
// 4 waves. A staged via global_load_lds (m97), W staged with fused fp32->bf16.
// MODE 0: fp32 out[m*1024+n]   MODE 1: q bf16 [B,H,T,64] scaled
// MODE 2: kv bf16 [B,G,T,64]   MODE 3: vT bf16 [B,G,64,T]
// ---------------------------------------------------------------------------
template <int MODE>
__global__ __launch_bounds__(256) void gemm_bt(const bf16* __restrict__ A,
                                               const float* __restrict__ W,
                                               void* __restrict__ out,
                                               float scale) {
  __shared__ alignas(16) bf16 As[128 * 32];
  __shared__ alignas(16) bf16 Bs[128 * 32];
  const int tid = threadIdx.x;
  const int lane = tid & 63;
  const int w = tid >> 6;
  const int wr = w >> 1, wc = w & 1;
  const int quad = lane >> 4, c = lane & 15;
  const int m0 = blockIdx.y * 128, n0 = blockIdx.x * 128;

  const int i0 = tid, i1 = tid + 256;
  const bf16* ga0 = A + (size_t)(m0 + (i0 >> 2)) * 1024 + (i0 & 3) * 8;
  const bf16* ga1 = A + (size_t)(m0 + (i1 >> 2)) * 1024 + (i1 & 3) * 8;

  floatx4 acc[4][4] = {};

  for (int kt = 0; kt < 32; ++kt) {
    if (kt) __syncthreads();  // all fragment reads of prev iter are drained
    __builtin_amdgcn_global_load_lds(GPTR(ga0), LPTR(&As[i0 * 8]), 16, 0, 0);
    __builtin_amdgcn_global_load_lds(GPTR(ga1), LPTR(&As[i1 * 8]), 16, 0, 0);
    ga0 += 32; ga1 += 32;
#pragma unroll
    for (int t = 0; t < 4; ++t) {  // W fp32 tile: convert-stage
      int idx = tid + t * 256;
      int row = idx >> 3, c4 = idx & 7;
      float4 v = *(const float4*)(W + (size_t)(n0 + row) * 1024 + kt * 32 + c4 * 4);
      alignas(8) bf16 tmp[4] = {__float2bfloat16(v.x), __float2bfloat16(v.y),
                                __float2bfloat16(v.z), __float2bfloat16(v.w)};
      *(uint64_t*)&Bs[row * 32 + c4 * 4] = *(const uint64_t*)tmp;
    }
    __syncthreads();
    bf16x8 af[4], bfr[4];
#pragma unroll
    for (int i = 0; i < 4; ++i)
      af[i] = *(const bf16x8*)&As[(wr * 64 + i * 16 + c) * 32 + quad * 8];
#pragma unroll
    for (int j = 0; j < 4; ++j)
      bfr[j] = *(const bf16x8*)&Bs[(wc * 64 + j * 16 + c) * 32 + quad * 8];
#pragma unroll
    for (int i = 0; i < 4; ++i)
#pragma unroll
      for (int j = 0; j < 4; ++j)
        acc[i][j] = mfma16(af[i], bfr[j], acc[i][j]);
  }

  if (MODE == 3) {  // vT[((b*4+g)*64+d)*1024+t], 4 consecutive t -> 8B store
#pragma unroll
    for (int i = 0; i < 4; ++i)
#pragma unroll
      for (int j = 0; j < 4; ++j) {
        int m = m0 + wr * 64 + i * 16 + quad * 4;
        int n = n0 + wc * 64 + j * 16 + c;
        int b = m >> 10, t = m & 1023, g = n >> 6, d = n & 63;
        alignas(8) bf16 tmp[4];
#pragma unroll
        for (int r = 0; r < 4; ++r) tmp[r] = __float2bfloat16(acc[i][j][r]);
        *(uint64_t*)((bf16*)out + (((size_t)(b * 4 + g)) * 64 + d) * 1024 + t) =
            *(const uint64_t*)tmp;
      }
    return;
  }

#pragma unroll
  for (int i = 0; i < 4; ++i)
#pragma unroll
    for (int j = 0; j < 4; ++j)
#pragma unroll
      for (int r = 0; r < 4; ++r) {
        int m = m0 + wr * 64 + i * 16 + quad * 4 + r;
        int n = n0 + wc * 64 + j * 16 + c;
        float v = acc[i][j][r] * scale;
        if (MODE == 0) {
          ((float*)out)[(size_t)m * 1024 + n] = v;
        } else if (MODE == 1) {
          int b = m >> 10, t = m & 1023, h = n >> 6, d = n & 63;
          ((bf16*)out)[(((size_t)(b * 16 + h)) * 1024 + t) * 64 + d] =
              __float2bfloat16(v);
        } else {
          int b = m >> 10, t = m & 1023, g = n >> 6, d = n & 63;
          ((bf16*)out)[(((size_t)(b * 4 + g)) * 1024 + t) * 64 + d] =
              __float2bfloat16(v);
        }
      }
}

// ---------------------------------------------------------------------------
// Flash attention, S-TRANSPOSED form: S^T = K.Q^T (swap MFMA operands).
// C-layout gives each lane 16 scores of ONE q-row (q = lane&15):
//  - softmax: in-reg reduce + 2 shfl_xor(16,32)
//  - P row per q: ds_write_b64 x4 -> ds_read_b128 x2  (stride 72: row base
//    144B = 16B aligned; bank starts (c*36+quad*4)%32 -> 2-way, free)
//  - all LDS rows wave/lane-private -> NO __syncthreads (waves drift freely);
//    same-wave write->read ordered via __threadfence_block()
// ROUND-5 BUG FIXED: rowP stride was 40 with writes up to offset 63 ->
// inter-row P corruption (absmax 3.2e-2). Now 72.
// LDS: qEl 64*264*2 + Pl 64*72*2 = 43008 B -> 3 blocks/CU.
// ---------------------------------------------------------------------------
__global__ __launch_bounds__(256, 3) void attn_kernel(
    const bf16* __restrict__ q_ws, const bf16* __restrict__ k_ws,
    const bf16* __restrict__ vT, const float* __restrict__ E,
    bf16* __restrict__ out) {
  __shared__ alignas(16) bf16 qEl[64 * 264];  // bias table, rows lane-private
  __shared__ alignas(16) bf16 Pl[64 * 72];    // P rows, lane-private
  const int tid = threadIdx.x;
  const int lane = tid & 63, w = tid >> 6;
  const int quad = lane >> 4, c = lane & 15;
  const int bh = blockIdx.y;
  const int b = bh >> 4, h = bh & 15, g = h >> 2;
  const int qb = blockIdx.x * 64 + w * 16;

  // Q fragment (same layout serves as A- or B-operand)
  const bf16* qrow = q_ws + ((size_t)bh * 1024 + qb + c) * 64;
  bf16x8 qf0 = *(const bf16x8*)(qrow + quad * 8);
  bf16x8 qf1 = *(const bf16x8*)(qrow + 32 + quad * 8);

  // qE[qlocal][p] = q.E[p]  (wave's rows w*16..w*16+15; p in [0,254])
  for (int jn = 0; jn < 16; ++jn) {
    int er = jn * 16 + c;
    er = er > 254 ? 254 : er;
    const float* Ep = E + (size_t)er * 64;
    float4 e0 = *(const float4*)(Ep + quad * 8);
    float4 e1 = *(const float4*)(Ep + quad * 8 + 4);
    float4 e2 = *(const float4*)(Ep + 32 + quad * 8);
    float4 e3 = *(const float4*)(Ep + 32 + quad * 8 + 4);
    alignas(16) bf16 t0b[8] = {
        __float2bfloat16(e0.x), __float2bfloat16(e0.y), __float2bfloat16(e0.z),
        __float2bfloat16(e0.w), __float2bfloat16(e1.x), __float2bfloat16(e1.y),
        __float2bfloat16(e1.z), __float2bfloat16(e1.w)};
    alignas(16) bf16 t1b[8] = {
        __float2bfloat16(e2.x), __float2bfloat16(e2.y), __float2bfloat16(e2.z),
        __float2bfloat16(e2.w), __float2bfloat16(e3.x), __float2bfloat16(e3.y),
        __float2bfloat16(e3.z), __float2bfloat16(e3.w)};
    floatx4 a = {};
    a = mfma16(qf0, *(const bf16x8*)t0b, a);
    a = mfma16(qf1, *(const bf16x8*)t1b, a);
#pragma unroll
    for (int r = 0; r < 4; ++r)
      qEl[(w * 16 + quad * 4 + r) * 264 + jn * 16 + c] = __float2bfloat16(a[r]);
  }
  __threadfence_block();
  __builtin_amdgcn_wave_barrier();

  const bf16* rowE = qEl + (size_t)(w * 16 + c) * 264;  // this lane's q-row
  bf16* rowP = Pl + (size_t)(w * 16 + c) * 72;
  const float blo = __bfloat162float(rowE[254]);  // dlt >= +127 (far past)
  const float bhi = __bfloat162float(rowE[0]);    // dlt <= -127 (far future)

  float mrow = -1e30f, lrow = 0.f;
  floatx4 o[4] = {};
  const bf16* kbase = k_ws + (size_t)(b * 4 + g) * 1024 * 64;
  const bf16* vbase = vT + (size_t)(b * 4 + g) * 64 * 1024;

  for (int t0 = 0; t0 < 1024; t0 += 64) {
    // S^T tiles: lane holds S[q=qb+c][kk=t0+j*16+quad*4+r]
    floatx4 S[4];
#pragma unroll
    for (int j = 0; j < 4; ++j) {
      const bf16* kp = kbase + (size_t)(t0 + j * 16 + c) * 64;
      bf16x8 kf0 = *(const bf16x8*)(kp + quad * 8);
      bf16x8 kf1 = *(const bf16x8*)(kp + 32 + quad * 8);
      floatx4 z = {};
      z = mfma16(kf0, qf0, z);
      S[j] = mfma16(kf1, qf1, z);
    }
    // bias
    const int dlt0 = qb + c - t0;
    if (t0 <= qb - 190) {  // wave-uniform: fully low-clamped (dlt >= 127)
#pragma unroll
      for (int j = 0; j < 4; ++j)
#pragma unroll
        for (int r = 0; r < 4; ++r) S[j][r] += blo;
    } else if (t0 >= qb + 142) {  // fully high-clamped (dlt <= -127)
#pragma unroll
      for (int j = 0; j < 4; ++j)
#pragma unroll
        for (int r = 0; r < 4; ++r) S[j][r] += bhi;
    } else {  // banded: gather from this lane's row
#pragma unroll
      for (int j = 0; j < 4; ++j)
#pragma unroll
        for (int r = 0; r < 4; ++r) {
          int dlt = dlt0 - j * 16 - quad * 4 - r;
          dlt = dlt > 127 ? 127 : (dlt < -127 ? -127 : dlt);
          S[j][r] += __bfloat162float(rowE[dlt + 127]);
        }
    }
    // online softmax: in-reg reduce + 2 shuffles
    float mx = -1e30f;
#pragma unroll
    for (int j = 0; j < 4; ++j)
#pragma unroll
      for (int r = 0; r < 4; ++r) mx = fmaxf(mx, S[j][r]);
    mx = fmaxf(mx, __shfl_xor(mx, 16, 64));
    mx = fmaxf(mx, __shfl_xor(mx, 32, 64));
    float nm = fmaxf(mrow, mx);
    float alpha = __expf(mrow - nm);
    float rs = 0.f;
#pragma unroll
    for (int j = 0; j < 4; ++j)
#pragma unroll
      for (int r = 0; r < 4; ++r) {
        float p = __expf(S[j][r] - nm);
        S[j][r] = p;
        rs += p;
      }
    rs += __shfl_xor(rs, 16, 64);
    rs += __shfl_xor(rs, 32, 64);
    lrow = lrow * alpha + rs;
    mrow = nm;
    // P -> LDS row (kk-consecutive quads of 4 -> b64 stores)
#pragma unroll
    for (int j = 0; j < 4; ++j) {
      alignas(8) bf16 tmp[4];
#pragma unroll
      for (int r = 0; r < 4; ++r) tmp[r] = __float2bfloat16(S[j][r]);
      *(uint64_t*)(rowP + j * 16 + quad * 4) = *(const uint64_t*)tmp;
    }
    // rescale O (rows q=quad*4+r need alpha from lane quad*4+r)
    float av[4];
#pragma unroll
    for (int r = 0; r < 4; ++r) av[r] = __shfl(alpha, quad * 4 + r, 64);
#pragma unroll
    for (int jj = 0; jj < 4; ++jj)
#pragma unroll
      for (int r = 0; r < 4; ++r) o[jj][r] *= av[r];
    __threadfence_block();
    __builtin_amdgcn_wave_barrier();
    bf16x8 pf0 = *(const bf16x8*)(rowP + quad * 8);
    bf16x8 pf1 = *(const bf16x8*)(rowP + 32 + quad * 8);
#pragma unroll
    for (int jj = 0; jj < 4; ++jj) {
      const bf16* vp = vbase + (size_t)(jj * 16 + c) * 1024 + t0;
      bf16x8 vf0 = *(const bf16x8*)(vp + quad * 8);
      bf16x8 vf1 = *(const bf16x8*)(vp + 32 + quad * 8);
      o[jj] = mfma16(pf0, vf0, o[jj]);
      o[jj] = mfma16(pf1, vf1, o[jj]);
    }
    __builtin_amdgcn_wave_barrier();  // keep pf reads before next overwrite
  }

  // epilogue: per-row l via shuffle, write bf16 attn [B,T,H,64]
  float lr4[4];
#pragma unroll
  for (int r = 0; r < 4; ++r) lr4[r] = __shfl(lrow, quad * 4 + r, 64);
#pragma unroll
  for (int jj = 0; jj < 4; ++jj)
#pragma unroll
    for (int r = 0; r < 4; ++r) {
      int qi = qb + quad * 4 + r;
      out[(((size_t)b * 1024 + qi) * 16 + h) * 64 + jj * 16 + c] =
          __float2bfloat16(o[jj][r] / lr4[r]);
    }
}

// ---------------------------------------------------------------------------
// Memory plan (ws stays at validated 24 MB):
//   d_out (32 MB fp32): [0,16M) q bf16 | [16M,32M) x_bf16 — both dead before
//   the final o-proj overwrites d_out.
//   ws: k 4MB @0 | vT 4MB @4M | attn(bf16) 16MB @8M.
// ---------------------------------------------------------------------------
extern "C" void kernel_launch(void* const* d_in, const int* in_sizes, int n_in,
                              void* d_out, int out_size, void* d_ws,
                              size_t ws_size, hipStream_t stream) {
  const float* x = (const float*)d_in[0];
  const float* Wq = (const float*)d_in[1];
  const float* Wk = (const float*)d_in[2];
  const float* Wv = (const float*)d_in[3];
  const float* Wo = (const float*)d_in[4];
  const float* E = (const float*)d_in[5];

  char* ws = (char*)d_ws;
  bf16* q_ws = (bf16*)d_out;                          // [0,16M)
  bf16* x_bf = (bf16*)((char*)d_out + (16ull << 20)); // [16M,32M)
  bf16* k_ws = (bf16*)(ws);
  bf16* vT = (bf16*)(ws + (4ull << 20));
  bf16* attn = (bf16*)(ws + (8ull << 20));
  float* outp = (float*)d_out;

  cvt_bf16<<<2048, 256, 0, stream>>>(x, x_bf, 8 * 1024 * 1024 / 4);
  gemm_bt<1><<<dim3(8, 64), 256, 0, stream>>>(x_bf, Wq, q_ws, 0.125f);
  gemm_bt<2><<<dim3(2, 64), 256, 0, stream>>>(x_bf, Wk, k_ws, 1.0f);
  gemm_bt<3><<<dim3(2, 64), 256, 0, stream>>>(x_bf, Wv, vT, 1.0f);
  attn_kernel<<<dim3(16, 128), 256, 0, stream>>>(q_ws, k_ws, vT, E, attn);
  gemm_bt<0><<<dim3(8, 64), 256, 0, stream>>>(attn, Wo, outp, 1.0f);
}

// Round 7
// 358.714 us; speedup vs baseline: 1.4942x; 1.4583x over previous
//
#include <hip/hip_runtime.h>
#include <hip/hip_bf16.h>
#include <cstdint>
#include <cstddef>

typedef __hip_bfloat16 bf16;
typedef __attribute__((ext_vector_type(8))) __bf16 bf16x8;
typedef __attribute__((ext_vector_type(4))) float floatx4;

#define GPTR(p) ((const __attribute__((address_space(1))) void*)(p))
#define LPTR(p) ((__attribute__((address_space(3))) void*)(p))

__device__ __forceinline__ floatx4 mfma16(bf16x8 a, bf16x8 b, floatx4 c) {
  return __builtin_amdgcn_mfma_f32_16x16x32_bf16(a, b, c, 0, 0, 0);
}

// ---------------------------------------------------------------------------
// fp32 -> bf16 bulk convert (x pre-cast)
// ---------------------------------------------------------------------------
__global__ __launch_bounds__(256) void cvt_bf16(const float* __restrict__ in,
                                                bf16* __restrict__ out, int n4) {
  for (int i = blockIdx.x * 256 + threadIdx.x; i < n4; i += gridDim.x * 256) {
    float4 v = ((const float4*)in)[i];
    alignas(8) bf16 t[4] = {__float2bfloat16(v.x), __float2bfloat16(v.y),
                            __float2bfloat16(v.z), __float2bfloat16(v.w)};
    *(uint64_t*)(out + (size_t)i * 4) = *(const uint64_t*)t;
  }
}

// ---------------------------------------------------------------------------
// GEMM: out = A[M,1024](bf16) @ W[N,1024](fp32)^T. 128x128 tile, BK=32,
// 4 waves. A staged via global_load_lds (m97), W staged with fused fp32->bf16.
// MODE 0: fp32 out[m*1024+n]   MODE 1: q bf16 [B,H,T,64] scaled
// MODE 2: kv bf16 [B,G,T,64]   MODE 3: vT bf16 [B,G,64,T]
// ---------------------------------------------------------------------------
template <int MODE>
__global__ __launch_bounds__(256) void gemm_bt(const bf16* __restrict__ A,
                                               const float* __restrict__ W,
                                               void* __restrict__ out,
                                               float scale) {
  __shared__ alignas(16) bf16 As[128 * 32];
  __shared__ alignas(16) bf16 Bs[128 * 32];
  const int tid = threadIdx.x;
  const int lane = tid & 63;
  const int w = tid >> 6;
  const int wr = w >> 1, wc = w & 1;
  const int quad = lane >> 4, c = lane & 15;
  const int m0 = blockIdx.y * 128, n0 = blockIdx.x * 128;

  const int i0 = tid, i1 = tid + 256;
  const bf16* ga0 = A + (size_t)(m0 + (i0 >> 2)) * 1024 + (i0 & 3) * 8;
  const bf16* ga1 = A + (size_t)(m0 + (i1 >> 2)) * 1024 + (i1 & 3) * 8;

  floatx4 acc[4][4] = {};

  for (int kt = 0; kt < 32; ++kt) {
    if (kt) __syncthreads();
    __builtin_amdgcn_global_load_lds(GPTR(ga0), LPTR(&As[i0 * 8]), 16, 0, 0);
    __builtin_amdgcn_global_load_lds(GPTR(ga1), LPTR(&As[i1 * 8]), 16, 0, 0);
    ga0 += 32; ga1 += 32;
#pragma unroll
    for (int t = 0; t < 4; ++t) {  // W fp32 tile: convert-stage
      int idx = tid + t * 256;
      int row = idx >> 3, c4 = idx & 7;
      float4 v = *(const float4*)(W + (size_t)(n0 + row) * 1024 + kt * 32 + c4 * 4);
      alignas(8) bf16 tmp[4] = {__float2bfloat16(v.x), __float2bfloat16(v.y),
                                __float2bfloat16(v.z), __float2bfloat16(v.w)};
      *(uint64_t*)&Bs[row * 32 + c4 * 4] = *(const uint64_t*)tmp;
    }
    __syncthreads();
    bf16x8 af[4], bfr[4];
#pragma unroll
    for (int i = 0; i < 4; ++i)
      af[i] = *(const bf16x8*)&As[(wr * 64 + i * 16 + c) * 32 + quad * 8];
#pragma unroll
    for (int j = 0; j < 4; ++j)
      bfr[j] = *(const bf16x8*)&Bs[(wc * 64 + j * 16 + c) * 32 + quad * 8];
#pragma unroll
    for (int i = 0; i < 4; ++i)
#pragma unroll
      for (int j = 0; j < 4; ++j)
        acc[i][j] = mfma16(af[i], bfr[j], acc[i][j]);
  }

  if (MODE == 3) {
#pragma unroll
    for (int i = 0; i < 4; ++i)
#pragma unroll
      for (int j = 0; j < 4; ++j) {
        int m = m0 + wr * 64 + i * 16 + quad * 4;
        int n = n0 + wc * 64 + j * 16 + c;
        int b = m >> 10, t = m & 1023, g = n >> 6, d = n & 63;
        alignas(8) bf16 tmp[4];
#pragma unroll
        for (int r = 0; r < 4; ++r) tmp[r] = __float2bfloat16(acc[i][j][r]);
        *(uint64_t*)((bf16*)out + (((size_t)(b * 4 + g)) * 64 + d) * 1024 + t) =
            *(const uint64_t*)tmp;
      }
    return;
  }

#pragma unroll
  for (int i = 0; i < 4; ++i)
#pragma unroll
    for (int j = 0; j < 4; ++j)
#pragma unroll
      for (int r = 0; r < 4; ++r) {
        int m = m0 + wr * 64 + i * 16 + quad * 4 + r;
        int n = n0 + wc * 64 + j * 16 + c;
        float v = acc[i][j][r] * scale;
        if (MODE == 0) {
          ((float*)out)[(size_t)m * 1024 + n] = v;
        } else if (MODE == 1) {
          int b = m >> 10, t = m & 1023, h = n >> 6, d = n & 63;
          ((bf16*)out)[(((size_t)(b * 16 + h)) * 1024 + t) * 64 + d] =
              __float2bfloat16(v);
        } else {
          int b = m >> 10, t = m & 1023, g = n >> 6, d = n & 63;
          ((bf16*)out)[(((size_t)(b * 4 + g)) * 1024 + t) * 64 + d] =
              __float2bfloat16(v);
        }
      }
}

// ---------------------------------------------------------------------------
// Staged 64x64 bf16 tile with XOR-8 column-block swizzle.
// LDS (r, cb) holds global (r, cb ^ (r&7)); read global (r,G) at
// r*64 + ((G ^ (r&7)) * 8). Staging keeps lane-linear LDS dests
// (global_load_lds wave-uniform-base rule, m104); the swizzle lives in the
// per-lane GLOBAL address, which is unconstrained.
// ---------------------------------------------------------------------------
__device__ __forceinline__ void stage_tile_swz(const bf16* __restrict__ g,
                                               int gstride, bf16* __restrict__ dst,
                                               int tid) {
#pragma unroll
  for (int s = 0; s < 2; ++s) {
    int f = s * 256 + tid;
    int r = f >> 3, cb = f & 7;
    int cbg = cb ^ (r & 7);
    __builtin_amdgcn_global_load_lds(GPTR(g + (size_t)r * gstride + cbg * 8),
                                     LPTR(dst + f * 8), 16, 0, 0);
  }
}

__device__ __forceinline__ bf16x8 read_frag_swz(const bf16* __restrict__ tile,
                                                int row, int cb) {
  return *(const bf16x8*)&tile[row * 64 + ((cb ^ (row & 7)) * 8)];
}

// ---------------------------------------------------------------------------
// Flash attention, S^T = K.Q^T form, m97-STAGED K-loop:
//  - K tile (64 keys x 64 d) and V^T tile (64 d x 64 t) staged to LDS once
//    per block via global_load_lds (round-6 version had each of the 4 waves
//    re-loading identical fragments from global: 4x vmem, latency-bound at
//    MfmaUtil 5%).
//  - P (stride-72 rows, lane-private) overlays the K buffer after barrier B.
//  - 3 __syncthreads/iter; barrier drains hidden by 3 blocks/CU (m114).
// LDS: qEl 33792 + K/P 9216 + V 8192 = 51200 B -> 3 blocks/CU.
// ---------------------------------------------------------------------------
__global__ __launch_bounds__(256, 3) void attn_kernel(
    const bf16* __restrict__ q_ws, const bf16* __restrict__ k_ws,
    const bf16* __restrict__ vT, const float* __restrict__ E,
    bf16* __restrict__ out) {
  __shared__ alignas(16) bf16 qEl[64 * 264];  // bias table, rows lane-private
  __shared__ alignas(16) bf16 Ks[64 * 72];    // K tile (staged 64x64) / P rows
  __shared__ alignas(16) bf16 Vs[64 * 64];    // V^T tile
  const int tid = threadIdx.x;
  const int lane = tid & 63, w = tid >> 6;
  const int quad = lane >> 4, c = lane & 15;
  const int bh = blockIdx.y;
  const int b = bh >> 4, h = bh & 15, g = h >> 2;
  const int qb = blockIdx.x * 64 + w * 16;

  // Q fragment (A/B-operand layout), stays in registers
  const bf16* qrow = q_ws + ((size_t)bh * 1024 + qb + c) * 64;
  bf16x8 qf0 = *(const bf16x8*)(qrow + quad * 8);
  bf16x8 qf1 = *(const bf16x8*)(qrow + 32 + quad * 8);

  // qE[qlocal][p] = q.E[p]  (wave's rows w*16..w*16+15; p in [0,254])
  for (int jn = 0; jn < 16; ++jn) {
    int er = jn * 16 + c;
    er = er > 254 ? 254 : er;
    const float* Ep = E + (size_t)er * 64;
    float4 e0 = *(const float4*)(Ep + quad * 8);
    float4 e1 = *(const float4*)(Ep + quad * 8 + 4);
    float4 e2 = *(const float4*)(Ep + 32 + quad * 8);
    float4 e3 = *(const float4*)(Ep + 32 + quad * 8 + 4);
    alignas(16) bf16 t0b[8] = {
        __float2bfloat16(e0.x), __float2bfloat16(e0.y), __float2bfloat16(e0.z),
        __float2bfloat16(e0.w), __float2bfloat16(e1.x), __float2bfloat16(e1.y),
        __float2bfloat16(e1.z), __float2bfloat16(e1.w)};
    alignas(16) bf16 t1b[8] = {
        __float2bfloat16(e2.x), __float2bfloat16(e2.y), __float2bfloat16(e2.z),
        __float2bfloat16(e2.w), __float2bfloat16(e3.x), __float2bfloat16(e3.y),
        __float2bfloat16(e3.z), __float2bfloat16(e3.w)};
    floatx4 a = {};
    a = mfma16(qf0, *(const bf16x8*)t0b, a);
    a = mfma16(qf1, *(const bf16x8*)t1b, a);
#pragma unroll
    for (int r = 0; r < 4; ++r)
      qEl[(w * 16 + quad * 4 + r) * 264 + jn * 16 + c] = __float2bfloat16(a[r]);
  }

  const bf16* rowE = qEl + (size_t)(w * 16 + c) * 264;  // this lane's q-row
  bf16* rowP = Ks + (size_t)(w * 16 + c) * 72;          // P overlay, stride 72
  float mrow = -1e30f, lrow = 0.f;
  floatx4 o[4] = {};
  const bf16* kbase = k_ws + (size_t)(b * 4 + g) * 1024 * 64;
  const bf16* vbase = vT + (size_t)(b * 4 + g) * 64 * 1024;
  float blo = 0.f, bhi = 0.f;  // valid after first barrier

  for (int t0 = 0; t0 < 1024; t0 += 64) {
    stage_tile_swz(kbase + (size_t)t0 * 64, 64, Ks, tid);
    stage_tile_swz(vbase + t0, 1024, Vs, tid);
    __syncthreads();  // A: staging landed (vmcnt drained at barrier)
    if (t0 == 0) {
      blo = __bfloat162float(rowE[254]);  // dlt >= +127 (far past)
      bhi = __bfloat162float(rowE[0]);    // dlt <= -127 (far future)
    }
    // S^T: lane holds S[q=qb+c][kk=t0+j*16+quad*4+r]
    floatx4 S[4];
#pragma unroll
    for (int j = 0; j < 4; ++j) {
      bf16x8 kf0 = read_frag_swz(Ks, j * 16 + c, quad);
      bf16x8 kf1 = read_frag_swz(Ks, j * 16 + c, quad + 4);
      floatx4 z = {};
      z = mfma16(kf0, qf0, z);
      S[j] = mfma16(kf1, qf1, z);
    }
    // bias
    const int dlt0 = qb + c - t0;
    if (t0 <= qb - 190) {
#pragma unroll
      for (int j = 0; j < 4; ++j)
#pragma unroll
        for (int r = 0; r < 4; ++r) S[j][r] += blo;
    } else if (t0 >= qb + 142) {
#pragma unroll
      for (int j = 0; j < 4; ++j)
#pragma unroll
        for (int r = 0; r < 4; ++r) S[j][r] += bhi;
    } else {
#pragma unroll
      for (int j = 0; j < 4; ++j)
#pragma unroll
        for (int r = 0; r < 4; ++r) {
          int dlt = dlt0 - j * 16 - quad * 4 - r;
          dlt = dlt > 127 ? 127 : (dlt < -127 ? -127 : dlt);
          S[j][r] += __bfloat162float(rowE[dlt + 127]);
        }
    }
    // online softmax: in-reg reduce + 2 shuffles
    float mx = -1e30f;
#pragma unroll
    for (int j = 0; j < 4; ++j)
#pragma unroll
      for (int r = 0; r < 4; ++r) mx = fmaxf(mx, S[j][r]);
    mx = fmaxf(mx, __shfl_xor(mx, 16, 64));
    mx = fmaxf(mx, __shfl_xor(mx, 32, 64));
    float nm = fmaxf(mrow, mx);
    float alpha = __expf(mrow - nm);
    float rs = 0.f;
#pragma unroll
    for (int j = 0; j < 4; ++j)
#pragma unroll
      for (int r = 0; r < 4; ++r) {
        float p = __expf(S[j][r] - nm);
        S[j][r] = p;
        rs += p;
      }
    rs += __shfl_xor(rs, 16, 64);
    rs += __shfl_xor(rs, 32, 64);
    lrow = lrow * alpha + rs;
    mrow = nm;
    __syncthreads();  // B: all waves consumed K frags; Ks region reusable
    // P -> Ks overlay (lane-private stride-72 rows, b64 stores)
#pragma unroll
    for (int j = 0; j < 4; ++j) {
      alignas(8) bf16 tmp[4];
#pragma unroll
      for (int r = 0; r < 4; ++r) tmp[r] = __float2bfloat16(S[j][r]);
      *(uint64_t*)(rowP + j * 16 + quad * 4) = *(const uint64_t*)tmp;
    }
    // rescale O (row q=quad*4+r gets alpha from lane quad*4+r)
    float av[4];
#pragma unroll
    for (int r = 0; r < 4; ++r) av[r] = __shfl(alpha, quad * 4 + r, 64);
#pragma unroll
    for (int jj = 0; jj < 4; ++jj)
#pragma unroll
      for (int r = 0; r < 4; ++r) o[jj][r] *= av[r];
    __threadfence_block();
    __builtin_amdgcn_wave_barrier();  // same-wave P write->read ordering
    bf16x8 pf0 = *(const bf16x8*)(rowP + quad * 8);
    bf16x8 pf1 = *(const bf16x8*)(rowP + 32 + quad * 8);
#pragma unroll
    for (int jj = 0; jj < 4; ++jj) {
      bf16x8 vf0 = read_frag_swz(Vs, jj * 16 + c, quad);
      bf16x8 vf1 = read_frag_swz(Vs, jj * 16 + c, quad + 4);
      o[jj] = mfma16(pf0, vf0, o[jj]);
      o[jj] = mfma16(pf1, vf1, o[jj]);
    }
    __syncthreads();  // C: P/V consumed; safe to restage
  }

  // epilogue: per-row l via shuffle, write bf16 attn [B,T,H,64]
  float lr4[4];
#pragma unroll
  for (int r = 0; r < 4; ++r) lr4[r] = __shfl(lrow, quad * 4 + r, 64);
#pragma unroll
  for (int jj = 0; jj < 4; ++jj)
#pragma unroll
    for (int r = 0; r < 4; ++r) {
      int qi = qb + quad * 4 + r;
      out[(((size_t)b * 1024 + qi) * 16 + h) * 64 + jj * 16 + c] =
          __float2bfloat16(o[jj][r] / lr4[r]);
    }
}

// ---------------------------------------------------------------------------
// Memory plan (ws 24 MB):
//   d_out (32 MB fp32): [0,16M) q bf16 | [16M,32M) x_bf16 — dead before the
//   final o-proj overwrites d_out.
//   ws: k 4MB @0 | vT 4MB @4M | attn(bf16) 16MB @8M.
// ---------------------------------------------------------------------------
extern "C" void kernel_launch(void* const* d_in, const int* in_sizes, int n_in,
                              void* d_out, int out_size, void* d_ws,
                              size_t ws_size, hipStream_t stream) {
  const float* x = (const float*)d_in[0];
  const float* Wq = (const float*)d_in[1];
  const float* Wk = (const float*)d_in[2];
  const float* Wv = (const float*)d_in[3];
  const float* Wo = (const float*)d_in[4];
  const float* E = (const float*)d_in[5];

  char* ws = (char*)d_ws;
  bf16* q_ws = (bf16*)d_out;                          // [0,16M)
  bf16* x_bf = (bf16*)((char*)d_out + (16ull << 20)); // [16M,32M)
  bf16* k_ws = (bf16*)(ws);
  bf16* vT = (bf16*)(ws + (4ull << 20));
  bf16* attn = (bf16*)(ws + (8ull << 20));
  float* outp = (float*)d_out;

  cvt_bf16<<<2048, 256, 0, stream>>>(x, x_bf, 8 * 1024 * 1024 / 4);
  gemm_bt<1><<<dim3(8, 64), 256, 0, stream>>>(x_bf, Wq, q_ws, 0.125f);
  gemm_bt<2><<<dim3(2, 64), 256, 0, stream>>>(x_bf, Wk, k_ws, 1.0f);
  gemm_bt<3><<<dim3(2, 64), 256, 0, stream>>>(x_bf, Wv, vT, 1.0f);
  attn_kernel<<<dim3(16, 128), 256, 0, stream>>>(q_ws, k_ws, vT, E, attn);
  gemm_bt<0><<<dim3(8, 64), 256, 0, stream>>>(attn, Wo, outp, 1.0f);
}

// Round 8
// 284.173 us; speedup vs baseline: 1.8861x; 1.2623x over previous
//
#include <hip/hip_runtime.h>
#include <hip/hip_bf16.h>
#include <cstdint>
#include <cstddef>

typedef __hip_bfloat16 bf16;
typedef __attribute__((ext_vector_type(8))) __bf16 bf16x8;
typedef __attribute__((ext_vector_type(4))) float floatx4;

#define GPTR(p) ((const __attribute__((address_space(1))) void*)(p))
#define LPTR(p) ((__attribute__((address_space(3))) void*)(p))

__device__ __forceinline__ floatx4 mfma16(bf16x8 a, bf16x8 b, floatx4 c) {
  return __builtin_amdgcn_mfma_f32_16x16x32_bf16(a, b, c, 0, 0, 0);
}

// ---------------------------------------------------------------------------
// fp32 -> bf16 bulk convert (x and weights pre-cast once; removes the 64x
// redundant per-block W conversion that made round-7 GEMMs VALU-bound)
// ---------------------------------------------------------------------------
__global__ __launch_bounds__(256) void cvt_bf16(const float* __restrict__ in,
                                                bf16* __restrict__ out, int n4) {
  for (int i = blockIdx.x * 256 + threadIdx.x; i < n4; i += gridDim.x * 256) {
    float4 v = ((const float4*)in)[i];
    alignas(8) bf16 t[4] = {__float2bfloat16(v.x), __float2bfloat16(v.y),
                            __float2bfloat16(v.z), __float2bfloat16(v.w)};
    *(uint64_t*)(out + (size_t)i * 4) = *(const uint64_t*)t;
  }
}

// ---------------------------------------------------------------------------
// Fused QKV projection: A[8192,1024](bf16) @ [Wq;Wk;Wv](bf16)^T.
// m97 structure: 128x128 tile, BK=32, both sides global_load_lds width=16.
// grid (12, 64): nb 0-7 -> q (scaled, [B,H,T,64]); 8-9 -> k [B,G,T,64];
// 10-11 -> vT [B,G,64,T] (packed 8B transposed stores).
// ---------------------------------------------------------------------------
__global__ __launch_bounds__(256) void gemm_qkv(
    const bf16* __restrict__ A, const bf16* __restrict__ Wq,
    const bf16* __restrict__ Wk, const bf16* __restrict__ Wv,
    bf16* __restrict__ qout, bf16* __restrict__ kout,
    bf16* __restrict__ vTout) {
  __shared__ alignas(16) bf16 As[128 * 32];
  __shared__ alignas(16) bf16 Bs[128 * 32];
  const int tid = threadIdx.x;
  const int lane = tid & 63;
  const int w = tid >> 6;
  const int wr = w >> 1, wc = w & 1;
  const int quad = lane >> 4, c = lane & 15;
  const int m0 = blockIdx.y * 128;
  const int nb = blockIdx.x;

  int mode, nloc;
  const bf16* Wp;
  if (nb < 8) {
    mode = 1; Wp = Wq + (size_t)nb * 128 * 1024; nloc = nb * 128;
  } else if (nb < 10) {
    mode = 2; Wp = Wk + (size_t)(nb - 8) * 128 * 1024; nloc = (nb - 8) * 128;
  } else {
    mode = 3; Wp = Wv + (size_t)(nb - 10) * 128 * 1024; nloc = (nb - 10) * 128;
  }

  const int i0 = tid, i1 = tid + 256;
  const bf16* ga0 = A + (size_t)(m0 + (i0 >> 2)) * 1024 + (i0 & 3) * 8;
  const bf16* ga1 = A + (size_t)(m0 + (i1 >> 2)) * 1024 + (i1 & 3) * 8;
  const bf16* gb0 = Wp + (size_t)(i0 >> 2) * 1024 + (i0 & 3) * 8;
  const bf16* gb1 = Wp + (size_t)(i1 >> 2) * 1024 + (i1 & 3) * 8;

  floatx4 acc[4][4] = {};

  for (int kt = 0; kt < 32; ++kt) {
    if (kt) __syncthreads();
    __builtin_amdgcn_global_load_lds(GPTR(ga0), LPTR(&As[i0 * 8]), 16, 0, 0);
    __builtin_amdgcn_global_load_lds(GPTR(ga1), LPTR(&As[i1 * 8]), 16, 0, 0);
    __builtin_amdgcn_global_load_lds(GPTR(gb0), LPTR(&Bs[i0 * 8]), 16, 0, 0);
    __builtin_amdgcn_global_load_lds(GPTR(gb1), LPTR(&Bs[i1 * 8]), 16, 0, 0);
    ga0 += 32; ga1 += 32; gb0 += 32; gb1 += 32;
    __syncthreads();
    bf16x8 af[4], bfr[4];
#pragma unroll
    for (int i = 0; i < 4; ++i)
      af[i] = *(const bf16x8*)&As[(wr * 64 + i * 16 + c) * 32 + quad * 8];
#pragma unroll
    for (int j = 0; j < 4; ++j)
      bfr[j] = *(const bf16x8*)&Bs[(wc * 64 + j * 16 + c) * 32 + quad * 8];
#pragma unroll
    for (int i = 0; i < 4; ++i)
#pragma unroll
      for (int j = 0; j < 4; ++j)
        acc[i][j] = mfma16(af[i], bfr[j], acc[i][j]);
  }

  if (mode == 3) {  // vT[((b*4+g)*64+d)*1024+t]: 4 consecutive t -> 8B store
#pragma unroll
    for (int i = 0; i < 4; ++i)
#pragma unroll
      for (int j = 0; j < 4; ++j) {
        int m = m0 + wr * 64 + i * 16 + quad * 4;
        int n = nloc + wc * 64 + j * 16 + c;
        int b = m >> 10, t = m & 1023, g = n >> 6, d = n & 63;
        alignas(8) bf16 tmp[4];
#pragma unroll
        for (int r = 0; r < 4; ++r) tmp[r] = __float2bfloat16(acc[i][j][r]);
        *(uint64_t*)(vTout + (((size_t)(b * 4 + g)) * 64 + d) * 1024 + t) =
            *(const uint64_t*)tmp;
      }
    return;
  }

  const float scale = (mode == 1) ? 0.125f : 1.0f;
#pragma unroll
  for (int i = 0; i < 4; ++i)
#pragma unroll
    for (int j = 0; j < 4; ++j)
#pragma unroll
      for (int r = 0; r < 4; ++r) {
        int m = m0 + wr * 64 + i * 16 + quad * 4 + r;
        int n = nloc + wc * 64 + j * 16 + c;
        int b = m >> 10, t = m & 1023;
        bf16 v = __float2bfloat16(acc[i][j][r] * scale);
        if (mode == 1) {
          int h = n >> 6;
          qout[(((size_t)(b * 16 + h)) * 1024 + t) * 64 + (n & 63)] = v;
        } else {
          int g = n >> 6;
          kout[(((size_t)(b * 4 + g)) * 1024 + t) * 64 + (n & 63)] = v;
        }
      }
}

// ---------------------------------------------------------------------------
// O-projection: attn[8192,1024](bf16) @ Wo(bf16)^T -> fp32 d_out.
// Same m97 dual global_load_lds staging.
// ---------------------------------------------------------------------------
__global__ __launch_bounds__(256) void gemm_o(const bf16* __restrict__ A,
                                              const bf16* __restrict__ W,
                                              float* __restrict__ out) {
  __shared__ alignas(16) bf16 As[128 * 32];
  __shared__ alignas(16) bf16 Bs[128 * 32];
  const int tid = threadIdx.x;
  const int lane = tid & 63;
  const int w = tid >> 6;
  const int wr = w >> 1, wc = w & 1;
  const int quad = lane >> 4, c = lane & 15;
  const int m0 = blockIdx.y * 128, n0 = blockIdx.x * 128;

  const int i0 = tid, i1 = tid + 256;
  const bf16* ga0 = A + (size_t)(m0 + (i0 >> 2)) * 1024 + (i0 & 3) * 8;
  const bf16* ga1 = A + (size_t)(m0 + (i1 >> 2)) * 1024 + (i1 & 3) * 8;
  const bf16* gb0 = W + (size_t)(n0 + (i0 >> 2)) * 1024 + (i0 & 3) * 8;
  const bf16* gb1 = W + (size_t)(n0 + (i1 >> 2)) * 1024 + (i1 & 3) * 8;

  floatx4 acc[4][4] = {};

  for (int kt = 0; kt < 32; ++kt) {
    if (kt) __syncthreads();
    __builtin_amdgcn_global_load_lds(GPTR(ga0), LPTR(&As[i0 * 8]), 16, 0, 0);
    __builtin_amdgcn_global_load_lds(GPTR(ga1), LPTR(&As[i1 * 8]), 16, 0, 0);
    __builtin_amdgcn_global_load_lds(GPTR(gb0), LPTR(&Bs[i0 * 8]), 16, 0, 0);
    __builtin_amdgcn_global_load_lds(GPTR(gb1), LPTR(&Bs[i1 * 8]), 16, 0, 0);
    ga0 += 32; ga1 += 32; gb0 += 32; gb1 += 32;
    __syncthreads();
    bf16x8 af[4], bfr[4];
#pragma unroll
    for (int i = 0; i < 4; ++i)
      af[i] = *(const bf16x8*)&As[(wr * 64 + i * 16 + c) * 32 + quad * 8];
#pragma unroll
    for (int j = 0; j < 4; ++j)
      bfr[j] = *(const bf16x8*)&Bs[(wc * 64 + j * 16 + c) * 32 + quad * 8];
#pragma unroll
    for (int i = 0; i < 4; ++i)
#pragma unroll
      for (int j = 0; j < 4; ++j)
        acc[i][j] = mfma16(af[i], bfr[j], acc[i][j]);
  }

#pragma unroll
  for (int i = 0; i < 4; ++i)
#pragma unroll
    for (int j = 0; j < 4; ++j)
#pragma unroll
      for (int r = 0; r < 4; ++r) {
        int m = m0 + wr * 64 + i * 16 + quad * 4 + r;
        int n = n0 + wc * 64 + j * 16 + c;
        out[(size_t)m * 1024 + n] = acc[i][j][r];
      }
}

// ---------------------------------------------------------------------------
// Staged 64x64 bf16 tile with XOR-8 column-block swizzle (round-7, verified).
// ---------------------------------------------------------------------------
__device__ __forceinline__ void stage_tile_swz(const bf16* __restrict__ g,
                                               int gstride, bf16* __restrict__ dst,
                                               int tid) {
#pragma unroll
  for (int s = 0; s < 2; ++s) {
    int f = s * 256 + tid;
    int r = f >> 3, cb = f & 7;
    int cbg = cb ^ (r & 7);
    __builtin_amdgcn_global_load_lds(GPTR(g + (size_t)r * gstride + cbg * 8),
                                     LPTR(dst + f * 8), 16, 0, 0);
  }
}

__device__ __forceinline__ bf16x8 read_frag_swz(const bf16* __restrict__ tile,
                                                int row, int cb) {
  return *(const bf16x8*)&tile[row * 64 + ((cb ^ (row & 7)) * 8)];
}

// ---------------------------------------------------------------------------
// Flash attention, S^T = K.Q^T form, staged K-loop (round-7, verified).
// LDS: qEl 33792 + K/P 9216 + V 8192 = 51200 B -> 3 blocks/CU.
// ---------------------------------------------------------------------------
__global__ __launch_bounds__(256, 3) void attn_kernel(
    const bf16* __restrict__ q_ws, const bf16* __restrict__ k_ws,
    const bf16* __restrict__ vT, const float* __restrict__ E,
    bf16* __restrict__ out) {
  __shared__ alignas(16) bf16 qEl[64 * 264];  // bias table, rows lane-private
  __shared__ alignas(16) bf16 Ks[64 * 72];    // K tile (staged 64x64) / P rows
  __shared__ alignas(16) bf16 Vs[64 * 64];    // V^T tile
  const int tid = threadIdx.x;
  const int lane = tid & 63, w = tid >> 6;
  const int quad = lane >> 4, c = lane & 15;
  const int bh = blockIdx.y;
  const int b = bh >> 4, h = bh & 15, g = h >> 2;
  const int qb = blockIdx.x * 64 + w * 16;

  const bf16* qrow = q_ws + ((size_t)bh * 1024 + qb + c) * 64;
  bf16x8 qf0 = *(const bf16x8*)(qrow + quad * 8);
  bf16x8 qf1 = *(const bf16x8*)(qrow + 32 + quad * 8);

  // qE[qlocal][p] = q.E[p]  (wave's rows w*16..w*16+15; p in [0,254])
  for (int jn = 0; jn < 16; ++jn) {
    int er = jn * 16 + c;
    er = er > 254 ? 254 : er;
    const float* Ep = E + (size_t)er * 64;
    float4 e0 = *(const float4*)(Ep + quad * 8);
    float4 e1 = *(const float4*)(Ep + quad * 8 + 4);
    float4 e2 = *(const float4*)(Ep + 32 + quad * 8);
    float4 e3 = *(const float4*)(Ep + 32 + quad * 8 + 4);
    alignas(16) bf16 t0b[8] = {
        __float2bfloat16(e0.x), __float2bfloat16(e0.y), __float2bfloat16(e0.z),
        __float2bfloat16(e0.w), __float2bfloat16(e1.x), __float2bfloat16(e1.y),
        __float2bfloat16(e1.z), __float2bfloat16(e1.w)};
    alignas(16) bf16 t1b[8] = {
        __float2bfloat16(e2.x), __float2bfloat16(e2.y), __float2bfloat16(e2.z),
        __float2bfloat16(e2.w), __float2bfloat16(e3.x), __float2bfloat16(e3.y),
        __float2bfloat16(e3.z), __float2bfloat16(e3.w)};
    floatx4 a = {};
    a = mfma16(qf0, *(const bf16x8*)t0b, a);
    a = mfma16(qf1, *(const bf16x8*)t1b, a);
#pragma unroll
    for (int r = 0; r < 4; ++r)
      qEl[(w * 16 + quad * 4 + r) * 264 + jn * 16 + c] = __float2bfloat16(a[r]);
  }

  const bf16* rowE = qEl + (size_t)(w * 16 + c) * 264;
  bf16* rowP = Ks + (size_t)(w * 16 + c) * 72;
  float mrow = -1e30f, lrow = 0.f;
  floatx4 o[4] = {};
  const bf16* kbase = k_ws + (size_t)(b * 4 + g) * 1024 * 64;
  const bf16* vbase = vT + (size_t)(b * 4 + g) * 64 * 1024;
  float blo = 0.f, bhi = 0.f;

  for (int t0 = 0; t0 < 1024; t0 += 64) {
    stage_tile_swz(kbase + (size_t)t0 * 64, 64, Ks, tid);
    stage_tile_swz(vbase + t0, 1024, Vs, tid);
    __syncthreads();  // A: staging landed
    if (t0 == 0) {
      blo = __bfloat162float(rowE[254]);
      bhi = __bfloat162float(rowE[0]);
    }
    floatx4 S[4];
#pragma unroll
    for (int j = 0; j < 4; ++j) {
      bf16x8 kf0 = read_frag_swz(Ks, j * 16 + c, quad);
      bf16x8 kf1 = read_frag_swz(Ks, j * 16 + c, quad + 4);
      floatx4 z = {};
      z = mfma16(kf0, qf0, z);
      S[j] = mfma16(kf1, qf1, z);
    }
    const int dlt0 = qb + c - t0;
    if (t0 <= qb - 190) {
#pragma unroll
      for (int j = 0; j < 4; ++j)
#pragma unroll
        for (int r = 0; r < 4; ++r) S[j][r] += blo;
    } else if (t0 >= qb + 142) {
#pragma unroll
      for (int j = 0; j < 4; ++j)
#pragma unroll
        for (int r = 0; r < 4; ++r) S[j][r] += bhi;
    } else {
#pragma unroll
      for (int j = 0; j < 4; ++j)
#pragma unroll
        for (int r = 0; r < 4; ++r) {
          int dlt = dlt0 - j * 16 - quad * 4 - r;
          dlt = dlt > 127 ? 127 : (dlt < -127 ? -127 : dlt);
          S[j][r] += __bfloat162float(rowE[dlt + 127]);
        }
    }
    float mx = -1e30f;
#pragma unroll
    for (int j = 0; j < 4; ++j)
#pragma unroll
      for (int r = 0; r < 4; ++r) mx = fmaxf(mx, S[j][r]);
    mx = fmaxf(mx, __shfl_xor(mx, 16, 64));
    mx = fmaxf(mx, __shfl_xor(mx, 32, 64));
    float nm = fmaxf(mrow, mx);
    float alpha = __expf(mrow - nm);
    float rs = 0.f;
#pragma unroll
    for (int j = 0; j < 4; ++j)
#pragma unroll
      for (int r = 0; r < 4; ++r) {
        float p = __expf(S[j][r] - nm);
        S[j][r] = p;
        rs += p;
      }
    rs += __shfl_xor(rs, 16, 64);
    rs += __shfl_xor(rs, 32, 64);
    lrow = lrow * alpha + rs;
    mrow = nm;
    __syncthreads();  // B: K frags consumed; Ks reusable as P
#pragma unroll
    for (int j = 0; j < 4; ++j) {
      alignas(8) bf16 tmp[4];
#pragma unroll
      for (int r = 0; r < 4; ++r) tmp[r] = __float2bfloat16(S[j][r]);
      *(uint64_t*)(rowP + j * 16 + quad * 4) = *(const uint64_t*)tmp;
    }
    float av[4];
#pragma unroll
    for (int r = 0; r < 4; ++r) av[r] = __shfl(alpha, quad * 4 + r, 64);
#pragma unroll
    for (int jj = 0; jj < 4; ++jj)
#pragma unroll
      for (int r = 0; r < 4; ++r) o[jj][r] *= av[r];
    __threadfence_block();
    __builtin_amdgcn_wave_barrier();
    bf16x8 pf0 = *(const bf16x8*)(rowP + quad * 8);
    bf16x8 pf1 = *(const bf16x8*)(rowP + 32 + quad * 8);
#pragma unroll
    for (int jj = 0; jj < 4; ++jj) {
      bf16x8 vf0 = read_frag_swz(Vs, jj * 16 + c, quad);
      bf16x8 vf1 = read_frag_swz(Vs, jj * 16 + c, quad + 4);
      o[jj] = mfma16(pf0, vf0, o[jj]);
      o[jj] = mfma16(pf1, vf1, o[jj]);
    }
    __syncthreads();  // C: P/V consumed; safe to restage
  }

  float lr4[4];
#pragma unroll
  for (int r = 0; r < 4; ++r) lr4[r] = __shfl(lrow, quad * 4 + r, 64);
#pragma unroll
  for (int jj = 0; jj < 4; ++jj)
#pragma unroll
    for (int r = 0; r < 4; ++r) {
      int qi = qb + quad * 4 + r;
      out[(((size_t)b * 1024 + qi) * 16 + h) * 64 + jj * 16 + c] =
          __float2bfloat16(o[jj][r] / lr4[r]);
    }
}

// ---------------------------------------------------------------------------
// Memory plan (ws stays at the PROVEN 24 MB; weights overlap dead regions):
//   d_out (32 MB fp32): [0,16M) q bf16 | [16M,32M) x_bf16 (both dead before
//     gemm_o overwrites d_out).
//   ws: k 4MB @0 | vT 4MB @4M | attn 16MB @8M
//   Wq/Wk/Wv_bf @8M/10M/10.5M  (inside attn region; dead before attn_kernel
//     writes it — stream-ordered).
//   Wo_bf @0 (inside k region; converted AFTER attn_kernel consumed k).
// ---------------------------------------------------------------------------
extern "C" void kernel_launch(void* const* d_in, const int* in_sizes, int n_in,
                              void* d_out, int out_size, void* d_ws,
                              size_t ws_size, hipStream_t stream) {
  const float* x = (const float*)d_in[0];
  const float* Wq = (const float*)d_in[1];
  const float* Wk = (const float*)d_in[2];
  const float* Wv = (const float*)d_in[3];
  const float* Wo = (const float*)d_in[4];
  const float* E = (const float*)d_in[5];

  char* ws = (char*)d_ws;
  bf16* q_ws = (bf16*)d_out;                           // [0,16M) of d_out
  bf16* x_bf = (bf16*)((char*)d_out + (16ull << 20));  // [16M,32M) of d_out
  bf16* k_ws = (bf16*)(ws);
  bf16* vT = (bf16*)(ws + (4ull << 20));
  bf16* attn = (bf16*)(ws + (8ull << 20));
  bf16* Wq_bf = (bf16*)(ws + (8ull << 20));            // 2 MB   (attn region)
  bf16* Wk_bf = (bf16*)(ws + (10ull << 20));           // 0.5 MB (attn region)
  bf16* Wv_bf = (bf16*)(ws + (10ull << 20) + (512ull << 10));  // 0.5 MB
  bf16* Wo_bf = (bf16*)(ws);                           // 2 MB   (k region)
  float* outp = (float*)d_out;

  cvt_bf16<<<2048, 256, 0, stream>>>(x, x_bf, 2097152);
  cvt_bf16<<<1024, 256, 0, stream>>>(Wq, Wq_bf, 262144);
  cvt_bf16<<<256, 256, 0, stream>>>(Wk, Wk_bf, 65536);
  cvt_bf16<<<256, 256, 0, stream>>>(Wv, Wv_bf, 65536);
  gemm_qkv<<<dim3(12, 64), 256, 0, stream>>>(x_bf, Wq_bf, Wk_bf, Wv_bf,
                                             q_ws, k_ws, vT);
  attn_kernel<<<dim3(16, 128), 256, 0, stream>>>(q_ws, k_ws, vT, E, attn);
  cvt_bf16<<<1024, 256, 0, stream>>>(Wo, Wo_bf, 262144);
  gemm_o<<<dim3(8, 64), 256, 0, stream>>>(attn, Wo_bf, outp);
}